// Round 9
// baseline (98.205 us; speedup 1.0000x reference)
//
#include <hip/hip_runtime.h>
#include <hip/hip_bf16.h>

// B=1024, K(conf)=256, D=1024, P=768.
// THREE dispatches (round-9: drop prep, fold fp32->bf16 into qk staging):
//  l1 (496 blocks): qk GEMM from fp32 inputs + cpT transpose  [R6/R7 verified]
//  scores (64 blocks): bf16 scores = q@km^T/32                [R4 verified]
//  out (256 blocks): out = J + softmax(scores)@cpT^T          [R4 verified]

typedef __attribute__((ext_vector_type(8))) short short8;   // 8 bf16
typedef __attribute__((ext_vector_type(4))) float f32x4;    // MFMA acc

__device__ __forceinline__ ushort f2bf(float x) {           // RNE
    union { float f; uint u; } c; c.f = x;
    return (ushort)((c.u + 0x7FFFu + ((c.u >> 16) & 1u)) >> 16);
}
__device__ __forceinline__ float bflo(uint u) {     // bf16 bits in LOW half
    union { uint u; float f; } c; c.u = u << 16; return c.f;
}
__device__ __forceinline__ float bfhi(uint u) {     // bf16 bits in HIGH half
    union { uint u; float f; } c; c.u = u & 0xFFFF0000u; return c.f;
}
__device__ __forceinline__ uint fbits(float x) {
    union { float f; uint u; } c; c.f = x; return c.u;
}
// pack two fp32 -> bf16 pair (lo = first), round-half-up
__device__ __forceinline__ uint pk_rhu(float lo, float hi) {
    return ((fbits(lo) + 0x8000u) >> 16) | ((fbits(hi) + 0x8000u) & 0xFFFF0000u);
}

#define MFMA_BF16 __builtin_amdgcn_mfma_f32_16x16x32_bf16

// ===========================================================================
// l1: blocks 0..239: q = J@Wq (192) | km = conf@Wk (48), fp32 inputs,
//     bf16 conversion fused into LDS staging. B operand is NN [k][n].
//     blocks 240..495: cpT[d][k] = bf16(conf[k][d] * prior[k]).
// (verbatim round-6/7 — passed twice, absmax 0.03125)
// ===========================================================================
union Lds1 {
    float tr[32][33];
    struct {
        __align__(16) ushort As[64][72];   // As[m][k]
        __align__(16) ushort Bs[64][72];   // Bs[n][k]
    } g;
};

__global__ __launch_bounds__(256)
void l1_kernel(const float* __restrict__ J, const float* __restrict__ conf,
               const float* __restrict__ prior, const float* __restrict__ Wq,
               const float* __restrict__ Wk, ushort* __restrict__ qb,
               ushort* __restrict__ kmb, ushort* __restrict__ cpT)
{
    __shared__ Lds1 S;
    const int t = threadIdx.x;
    const int bid = blockIdx.x;

    if (bid >= 240) {   // ---- cpT transpose (256 tiles of 32x32) ----
        const int b2 = bid - 240;
        const int rt = b2 >> 5, ct = b2 & 31;
        {
            const int row = t >> 3, c4 = (t & 7) << 2;
            const float4 v = *(const float4*)(conf + (size_t)(rt * 32 + row) * 1024 + ct * 32 + c4);
            const float p = prior[rt * 32 + row];
            S.tr[row][c4 + 0] = v.x * p; S.tr[row][c4 + 1] = v.y * p;
            S.tr[row][c4 + 2] = v.z * p; S.tr[row][c4 + 3] = v.w * p;
        }
        __syncthreads();
        {
            const int orow = t >> 3, oc4 = (t & 7) << 2;
            ushort4 o;
            o.x = f2bf(S.tr[oc4 + 0][orow]); o.y = f2bf(S.tr[oc4 + 1][orow]);
            o.z = f2bf(S.tr[oc4 + 2][orow]); o.w = f2bf(S.tr[oc4 + 3][orow]);
            *(ushort4*)(cpT + (size_t)(ct * 32 + orow) * 256 + rt * 32 + oc4) = o;
        }
        return;
    }

    // ---- qk GEMM ----
    const float *A, *Bm; ushort* C; int m0, n0;
    if (bid < 192) { A = J;    Bm = Wq; C = qb;  m0 = (bid / 12) * 64; n0 = (bid % 12) * 64; }
    else { const int b2 = bid - 192;
           A = conf; Bm = Wk; C = kmb; m0 = (b2  / 12) * 64; n0 = (b2  % 12) * 64; }

    const int wave = t >> 6, lane = t & 63;
    const int wm = (wave >> 1) * 32, wn = (wave & 1) * 32;
    const int lrow = lane & 15, quad = lane >> 4, lko = quad * 8;

    f32x4 acc[2][2];
    #pragma unroll
    for (int i = 0; i < 2; ++i)
        #pragma unroll
        for (int j = 0; j < 2; ++j) acc[i][j] = (f32x4)0.0f;

    const int sr = t >> 2, q4 = (t & 3) << 4;
    const int bn = (t & 15) << 2, bk = (t >> 4) << 1;
    const float* Ap = A + (size_t)(m0 + sr) * 1024 + q4;
    const float* Bp = Bm + (size_t)bk * 768 + n0 + bn;

    float4 aF0 = *(const float4*)(Ap + 0),  aF1 = *(const float4*)(Ap + 4);
    float4 aF2 = *(const float4*)(Ap + 8),  aF3 = *(const float4*)(Ap + 12);
    float4 bF0 = *(const float4*)(Bp);
    float4 bF1 = *(const float4*)(Bp + 768);
    float4 bF2 = *(const float4*)(Bp + (size_t)32 * 768);
    float4 bF3 = *(const float4*)(Bp + (size_t)33 * 768);

    for (int k0 = 0; k0 < 1024; k0 += 64) {
        {
            uint2 w;
            w.x = pk_rhu(aF0.x, aF0.y); w.y = pk_rhu(aF0.z, aF0.w);
            *(uint2*)&S.g.As[sr][q4 + 0] = w;
            w.x = pk_rhu(aF1.x, aF1.y); w.y = pk_rhu(aF1.z, aF1.w);
            *(uint2*)&S.g.As[sr][q4 + 4] = w;
            w.x = pk_rhu(aF2.x, aF2.y); w.y = pk_rhu(aF2.z, aF2.w);
            *(uint2*)&S.g.As[sr][q4 + 8] = w;
            w.x = pk_rhu(aF3.x, aF3.y); w.y = pk_rhu(aF3.z, aF3.w);
            *(uint2*)&S.g.As[sr][q4 + 12] = w;
            *(uint*)&S.g.Bs[bn + 0][bk]      = pk_rhu(bF0.x, bF1.x);
            *(uint*)&S.g.Bs[bn + 1][bk]      = pk_rhu(bF0.y, bF1.y);
            *(uint*)&S.g.Bs[bn + 2][bk]      = pk_rhu(bF0.z, bF1.z);
            *(uint*)&S.g.Bs[bn + 3][bk]      = pk_rhu(bF0.w, bF1.w);
            *(uint*)&S.g.Bs[bn + 0][bk + 32] = pk_rhu(bF2.x, bF3.x);
            *(uint*)&S.g.Bs[bn + 1][bk + 32] = pk_rhu(bF2.y, bF3.y);
            *(uint*)&S.g.Bs[bn + 2][bk + 32] = pk_rhu(bF2.z, bF3.z);
            *(uint*)&S.g.Bs[bn + 3][bk + 32] = pk_rhu(bF2.w, bF3.w);
        }
        __syncthreads();
        if (k0 + 64 < 1024) {
            aF0 = *(const float4*)(Ap + k0 + 64);
            aF1 = *(const float4*)(Ap + k0 + 68);
            aF2 = *(const float4*)(Ap + k0 + 72);
            aF3 = *(const float4*)(Ap + k0 + 76);
            const float* Bn = Bp + (size_t)(k0 + 64) * 768;
            bF0 = *(const float4*)(Bn);
            bF1 = *(const float4*)(Bn + 768);
            bF2 = *(const float4*)(Bn + (size_t)32 * 768);
            bF3 = *(const float4*)(Bn + (size_t)33 * 768);
        }
        #pragma unroll
        for (int kk = 0; kk < 64; kk += 32) {
            const short8 a0 = *(const short8*)&S.g.As[wm + lrow][kk + lko];
            const short8 a1 = *(const short8*)&S.g.As[wm + 16 + lrow][kk + lko];
            const short8 b0 = *(const short8*)&S.g.Bs[wn + lrow][kk + lko];
            const short8 b1 = *(const short8*)&S.g.Bs[wn + 16 + lrow][kk + lko];
            acc[0][0] = MFMA_BF16(a0, b0, acc[0][0], 0, 0, 0);
            acc[0][1] = MFMA_BF16(a0, b1, acc[0][1], 0, 0, 0);
            acc[1][0] = MFMA_BF16(a1, b0, acc[1][0], 0, 0, 0);
            acc[1][1] = MFMA_BF16(a1, b1, acc[1][1], 0, 0, 0);
        }
        __syncthreads();
    }

    #pragma unroll
    for (int i = 0; i < 2; ++i)
        #pragma unroll
        for (int j = 0; j < 2; ++j)
            #pragma unroll
            for (int r = 0; r < 4; ++r) {
                const int m = m0 + wm + i * 16 + quad * 4 + r;
                const int n = n0 + wn + j * 16 + lrow;
                C[(size_t)m * 768 + n] = f2bf(acc[i][j][r]);
            }
}

// ---------------------------------------------------------------------------
// scores(bf16) = (qb @ kmb^T) / 32  [1024,256], 64 blocks (round-4 verbatim)
// ---------------------------------------------------------------------------
__global__ __launch_bounds__(256)
void scores_kernel(const ushort* __restrict__ qb, const ushort* __restrict__ kmb,
                   ushort* __restrict__ sc)
{
    __shared__ __align__(16) ushort As[64][72];
    __shared__ __align__(16) ushort Bs[64][72];

    const int t = threadIdx.x;
    const int m0 = blockIdx.y * 64, n0 = blockIdx.x * 64;
    const int wave = t >> 6, lane = t & 63;
    const int wm = (wave >> 1) * 32, wn = (wave & 1) * 32;
    const int lrow = lane & 15, quad = lane >> 4, lko = quad * 8;

    f32x4 acc[2][2];
    #pragma unroll
    for (int i = 0; i < 2; ++i)
        #pragma unroll
        for (int j = 0; j < 2; ++j) acc[i][j] = (f32x4)0.0f;

    const int sr = t >> 2, sk = (t & 3) << 4;
    const ushort* Ap = qb  + (size_t)(m0 + sr) * 768 + sk;
    const ushort* Bp = kmb + (size_t)(n0 + sr) * 768 + sk;

    uint4 av0 = *(const uint4*)(Ap);
    uint4 av1 = *(const uint4*)(Ap + 8);
    uint4 bv0 = *(const uint4*)(Bp);
    uint4 bv1 = *(const uint4*)(Bp + 8);

    for (int k0 = 0; k0 < 768; k0 += 64) {
        *(uint4*)&As[sr][sk]     = av0;
        *(uint4*)&As[sr][sk + 8] = av1;
        *(uint4*)&Bs[sr][sk]     = bv0;
        *(uint4*)&Bs[sr][sk + 8] = bv1;
        __syncthreads();
        if (k0 + 64 < 768) {
            av0 = *(const uint4*)(Ap + k0 + 64);
            av1 = *(const uint4*)(Ap + k0 + 72);
            bv0 = *(const uint4*)(Bp + k0 + 64);
            bv1 = *(const uint4*)(Bp + k0 + 72);
        }
        #pragma unroll
        for (int kk = 0; kk < 64; kk += 32) {
            const short8 a0 = *(const short8*)&As[wm + lrow][kk + lko];
            const short8 a1 = *(const short8*)&As[wm + 16 + lrow][kk + lko];
            const short8 b0 = *(const short8*)&Bs[wn + lrow][kk + lko];
            const short8 b1 = *(const short8*)&Bs[wn + 16 + lrow][kk + lko];
            acc[0][0] = MFMA_BF16(a0, b0, acc[0][0], 0, 0, 0);
            acc[0][1] = MFMA_BF16(a0, b1, acc[0][1], 0, 0, 0);
            acc[1][0] = MFMA_BF16(a1, b0, acc[1][0], 0, 0, 0);
            acc[1][1] = MFMA_BF16(a1, b1, acc[1][1], 0, 0, 0);
        }
        __syncthreads();
    }

    #pragma unroll
    for (int i = 0; i < 2; ++i)
        #pragma unroll
        for (int j = 0; j < 2; ++j)
            #pragma unroll
            for (int r = 0; r < 4; ++r) {
                const int m = m0 + wm + i * 16 + quad * 4 + r;
                const int n = n0 + wn + j * 16 + lrow;
                sc[(size_t)m * 256 + n] = f2bf(acc[i][j][r] * 0.03125f);
            }
}

// ---------------------------------------------------------------------------
// out = J + softmax(scores) @ cpT^T. Grid (16,16), 64x64 tile (round-4 verbatim)
// ---------------------------------------------------------------------------
__global__ __launch_bounds__(256)
void out_kernel(const ushort* __restrict__ sc, const ushort* __restrict__ cpT,
                const float* __restrict__ J, float* __restrict__ out)
{
    __shared__ __align__(16) ushort At[64][264];
    __shared__ __align__(16) ushort Bs[64][72];
    __shared__ float rowInv[64];

    const int t = threadIdx.x;
    const int m0 = blockIdx.y * 64, n0 = blockIdx.x * 64;

    {   // softmax prologue: 4 threads/row, unnormalized exp -> LDS bf16
        const int row = t >> 2;
        const int cb  = (t & 3) * 64;
        const ushort* srow = sc + (size_t)(m0 + row) * 256 + cb;
        uint4 s[8];
        #pragma unroll
        for (int i = 0; i < 8; ++i) s[i] = *(const uint4*)(srow + i * 8);

        float mx = -1e30f;
        #pragma unroll
        for (int i = 0; i < 8; ++i) {
            mx = fmaxf(mx, fmaxf(fmaxf(bflo(s[i].x), bfhi(s[i].x)),
                                 fmaxf(bflo(s[i].y), bfhi(s[i].y))));
            mx = fmaxf(mx, fmaxf(fmaxf(bflo(s[i].z), bfhi(s[i].z)),
                                 fmaxf(bflo(s[i].w), bfhi(s[i].w))));
        }
        mx = fmaxf(mx, __shfl_xor(mx, 1));
        mx = fmaxf(mx, __shfl_xor(mx, 2));

        float sum = 0.0f;
        #pragma unroll
        for (int i = 0; i < 8; ++i) {
            uint4 o;
            uint* su = (uint*)&s[i];
            uint* ou = (uint*)&o;
            #pragma unroll
            for (int w = 0; w < 4; ++w) {
                const ushort e0 = f2bf(__expf(bflo(su[w]) - mx));
                const ushort e1 = f2bf(__expf(bfhi(su[w]) - mx));
                sum += bflo((uint)e0) + bflo((uint)e1);
                ou[w] = (uint)e0 | ((uint)e1 << 16);
            }
            *(uint4*)&At[row][cb + i * 8] = o;
        }
        sum += __shfl_xor(sum, 1);
        sum += __shfl_xor(sum, 2);
        if ((t & 3) == 0) rowInv[row] = 1.0f / sum;
    }
    __syncthreads();

    const int wave = t >> 6, lane = t & 63;
    const int wm = (wave >> 1) * 32, wn = (wave & 1) * 32;
    const int lrow = lane & 15, quad = lane >> 4, lko = quad * 8;

    f32x4 acc[2][2];
    #pragma unroll
    for (int i = 0; i < 2; ++i)
        #pragma unroll
        for (int j = 0; j < 2; ++j) acc[i][j] = (f32x4)0.0f;

    const int sr = t >> 2, sk = (t & 3) << 4;
    const ushort* Bp = cpT + (size_t)(n0 + sr) * 256 + sk;
    uint4 bv0 = *(const uint4*)(Bp);
    uint4 bv1 = *(const uint4*)(Bp + 8);

    for (int k0 = 0; k0 < 256; k0 += 64) {
        *(uint4*)&Bs[sr][sk]     = bv0;
        *(uint4*)&Bs[sr][sk + 8] = bv1;
        __syncthreads();
        if (k0 + 64 < 256) {
            bv0 = *(const uint4*)(Bp + k0 + 64);
            bv1 = *(const uint4*)(Bp + k0 + 72);
        }
        #pragma unroll
        for (int kk = 0; kk < 64; kk += 32) {
            const short8 a0 = *(const short8*)&At[wm + lrow][k0 + kk + lko];
            const short8 a1 = *(const short8*)&At[wm + 16 + lrow][k0 + kk + lko];
            const short8 b0 = *(const short8*)&Bs[wn + lrow][kk + lko];
            const short8 b1 = *(const short8*)&Bs[wn + 16 + lrow][kk + lko];
            acc[0][0] = MFMA_BF16(a0, b0, acc[0][0], 0, 0, 0);
            acc[0][1] = MFMA_BF16(a0, b1, acc[0][1], 0, 0, 0);
            acc[1][0] = MFMA_BF16(a1, b0, acc[1][0], 0, 0, 0);
            acc[1][1] = MFMA_BF16(a1, b1, acc[1][1], 0, 0, 0);
        }
        __syncthreads();
    }

    #pragma unroll
    for (int i = 0; i < 2; ++i)
        #pragma unroll
        for (int j = 0; j < 2; ++j)
            #pragma unroll
            for (int r = 0; r < 4; ++r) {
                const int mrel = wm + i * 16 + quad * 4 + r;
                const int m = m0 + mrel;
                const int n = n0 + wn + j * 16 + lrow;
                const size_t off = (size_t)m * 1024 + n;
                out[off] = acc[i][j][r] * rowInv[mrel] + J[off];
            }
}

extern "C" void kernel_launch(void* const* d_in, const int* in_sizes, int n_in,
                              void* d_out, int out_size, void* d_ws, size_t ws_size,
                              hipStream_t stream)
{
    const float* J     = (const float*)d_in[0];
    const float* conf  = (const float*)d_in[1];
    const float* prior = (const float*)d_in[2];
    const float* Wq    = (const float*)d_in[3];
    const float* Wk    = (const float*)d_in[4];
    float* out = (float*)d_out;

    ushort* ws  = (ushort*)d_ws;
    ushort* qb  = ws;               // 1024*768
    ushort* kmb = qb  + 786432;     // 256*768
    ushort* cpT = kmb + 196608;     // 1024*256
    ushort* scb = cpT + 262144;     // 1024*256 bf16 scores (~3 MB total)

    l1_kernel<<<496, 256, 0, stream>>>(J, conf, prior, Wq, Wk, qb, kmb, cpT);
    scores_kernel<<<dim3(4, 16), 256, 0, stream>>>(qb, kmb, scb);
    out_kernel<<<dim3(16, 16), 256, 0, stream>>>(scb, cpT, J, out);
}